// Round 17
// baseline (264.707 us; speedup 1.0000x reference)
//
#include <hip/hip_runtime.h>
#include <hip/hip_bf16.h>

#define NTOK 16384
#define HID 7168
#define NEXP 256
#define TOPK 8
#define NCHK 14            // mega-chunks of 512 k
#define CSTEP 32           // 16-k steps per chunk

typedef __bf16 bf16x8 __attribute__((ext_vector_type(8)));
typedef float  f32x16 __attribute__((ext_vector_type(16)));

// Weights, MFMA-fragment-linear (R12/R16-proven layout):
// uint4 idx = ((p8*8 + g)*8 + ks)*64 + lane holds
// B[e = g*32 + (lane&31)][k = p8*128 + ks*16 + (lane>>5)*8 .. +8]
__device__ __align__(16) unsigned short g_wb[NEXP * HID];

__device__ __forceinline__ unsigned int f2bfb(float x) {
    unsigned int u = __float_as_uint(x);
    return (u + 0x7fffu + ((u >> 16) & 1u)) >> 16;
}
__device__ __forceinline__ uint4 pk4(float4 p, float4 q) {
    uint4 u;
    u.x = f2bfb(p.x) | (f2bfb(p.y) << 16);
    u.y = f2bfb(p.z) | (f2bfb(p.w) << 16);
    u.z = f2bfb(q.x) | (f2bfb(q.y) << 16);
    u.w = f2bfb(q.z) | (f2bfb(q.w) << 16);
    return u;
}
__device__ __forceinline__ bf16x8 asbf8(uint4 u) {
    union { uint4 a; bf16x8 b; } c; c.a = u; return c.b;
}

__global__ void wconv_frag(const float* __restrict__ wt) {
    const int tid = blockIdx.x * 256 + threadIdx.x;
    const int l  = tid & 63;
    const int ks = (tid >> 6) & 7;
    const int g  = (tid >> 9) & 7;
    const int p  = tid >> 12;
    const int e  = g * 32 + (l & 31);
    const int kb = p * 128 + ks * 16 + ((l >> 5) << 3);
    const float4* s = (const float4*)(wt + (size_t)e * HID + kb);
    ((uint4*)g_wb)[tid] = pk4(s[0], s[1]);
}

__global__ void moe_rows(float* __restrict__ ob) {
    const int q = blockIdx.x * 256 + threadIdx.x;
    ob[262144 + q] = (float)((q & 7) * NTOK + (q >> 3));
}

// 512 blocks x 512 thr (8 waves). Wave w: 32 tokens x experts [w*32,+32),
// acc 16 VGPR. A: 14 mega-chunks (32 tok x 512 k bf16 = 32 KB LDS, XOR-swz).
// B: depth-8 per-wave register pipeline from fragment-linear g_wb, vmcnt(7).
// K-stagger + XCD swizzle de-hot-spot g_wb. LDS 33 KB -> 2 blocks/CU.
__global__ __launch_bounds__(512, 4) void moe_gate_v17(
    const float* __restrict__ hs,
    float* __restrict__ ob)
{
    __shared__ __align__(16) char smem[33792];

    const int tid   = threadIdx.x;
    const int lane  = tid & 63;
    const int w     = tid >> 6;        // 0..7 = expert group
    const int khalf = lane >> 5;
    const int bid   = blockIdx.x;
    const int sb    = (bid & 7) * 64 + (bid >> 3);   // XCD swizzle (512 = 8x64)
    const int t0    = sb * 32;
    const int boff  = bid % NCHK;                    // K-stagger

    // ---- A staging: thread covers row tid>>4, k-range [(tid&15)*32, +32) ----
    const int srow = tid >> 4;
    const int ssub = tid & 15;
    const float* astage = hs + (size_t)(t0 + srow) * HID + ssub * 32;
    int adst[4];
    #pragma unroll
    for (int d = 0; d < 4; ++d)
        adst[d] = srow * 1024 + (((ssub * 4 + d) ^ (srow & 7)) << 4);

    // ---- A fragment read geometry ----
    const int arow  = lane & 31;
    const int abase = arow * 1024;
    const int amask = arow & 7;

    // ---- B per-lane fragment-linear base (group g = w) ----
    const char* const bbase = (const char*)g_wb + w * 8192 + lane * 16;

    f32x16 acc = {};
    uint4 b0, b1, b2, b3, b4, b5, b6, b7;   // depth-8, static names

#define BADDR(J16) (bbase + (size_t)(((J16) >> 3) * 64 + ((J16) & 7)) * 1024)
#define LOADB(R, J16)                                                         \
    do { R = *(const uint4*)BADDR(J16); __builtin_amdgcn_sched_barrier(0); } while (0)
#define CMP(J, R)                                                             \
    do {                                                                      \
        const int off = ((((J) * 2 + khalf) ^ amask) << 4);                   \
        bf16x8 a = *(const bf16x8*)(smem + abase + off);                      \
        acc = __builtin_amdgcn_mfma_f32_32x32x16_bf16(a, asbf8(R), acc, 0, 0, 0); \
    } while (0)
#define VMW(N)                                                                \
    do {                                                                      \
        asm volatile("s_waitcnt vmcnt(" #N ")" ::: "memory");                 \
        __builtin_amdgcn_sched_barrier(0);                                    \
    } while (0)

    for (int c = 0; c < NCHK; ++c) {
        int cc = c + boff; if (cc >= NCHK) cc -= NCHK;

        __syncthreads();                 // prior chunk's LDS reads complete
        #pragma unroll
        for (int d = 0; d < 4; ++d) {
            float4 v0 = *(const float4*)(astage + (size_t)cc * 512 + d * 8);
            float4 v1 = *(const float4*)(astage + (size_t)cc * 512 + d * 8 + 4);
            *(uint4*)(smem + adst[d]) = pk4(v0, v1);
        }
        __syncthreads();                 // chunk staged

        const int J0 = cc * CSTEP;
        // depth-8 prologue
        LOADB(b0, J0 + 0); LOADB(b1, J0 + 1); LOADB(b2, J0 + 2); LOADB(b3, J0 + 3);
        LOADB(b4, J0 + 4); LOADB(b5, J0 + 5); LOADB(b6, J0 + 6); LOADB(b7, J0 + 7);

        // 24 steady steps (reload 8 ahead), fully static
        #pragma unroll
        for (int jj = 0; jj < 3; ++jj) {
            const int j = jj * 8;
            VMW(7); CMP(j + 0, b0); LOADB(b0, J0 + j +  8);
            VMW(7); CMP(j + 1, b1); LOADB(b1, J0 + j +  9);
            VMW(7); CMP(j + 2, b2); LOADB(b2, J0 + j + 10);
            VMW(7); CMP(j + 3, b3); LOADB(b3, J0 + j + 11);
            VMW(7); CMP(j + 4, b4); LOADB(b4, J0 + j + 12);
            VMW(7); CMP(j + 5, b5); LOADB(b5, J0 + j + 13);
            VMW(7); CMP(j + 6, b6); LOADB(b6, J0 + j + 14);
            VMW(7); CMP(j + 7, b7); LOADB(b7, J0 + j + 15);
        }
        // tail: drain
        VMW(7); CMP(24, b0);
        VMW(6); CMP(25, b1);
        VMW(5); CMP(26, b2);
        VMW(4); CMP(27, b3);
        VMW(3); CMP(28, b4);
        VMW(2); CMP(29, b5);
        VMW(1); CMP(30, b6);
        VMW(0); CMP(31, b7);
    }

    __syncthreads();                     // alias smem for epilogue

    // ---- epilogue: logits [32][257] f32 ----
    float* ll = (float*)smem;
    {
        const int ec = w * 32 + (lane & 31);
        #pragma unroll
        for (int r = 0; r < 16; ++r) {
            const int tok = (r & 3) + 8 * (r >> 2) + 4 * khalf;
            ll[tok * 257 + ec] = acc[r];
        }
    }
    __syncthreads();

    if (tid < 32) {
        const float* lr = ll + tid * 257;
        float bv[TOPK]; int bi8[TOPK];
        #pragma unroll
        for (int k = 0; k < TOPK; ++k) { bv[k] = -1e30f; bi8[k] = 0; }
        for (int e = 0; e < NEXP; ++e) {
            const float v = lr[e];
            if (v > bv[TOPK - 1]) {
                int k = TOPK - 1;
                while (k > 0 && v > bv[k - 1]) {
                    bv[k] = bv[k - 1]; bi8[k] = bi8[k - 1]; --k;
                }
                bv[k] = v; bi8[k] = e;      // strict > : ties keep lower idx
            }
        }
        float ev[TOPK], ssum = 0.f;
        #pragma unroll
        for (int r = 0; r < TOPK; ++r) { ev[r] = expf(bv[r] - bv[0]); ssum += ev[r]; }
        const float inv = 1.0f / ssum;

        const int tg = t0 + tid;
        #pragma unroll
        for (int r = 0; r < TOPK; ++r) {
            ob[(size_t)tg * TOPK + r]          = (float)bi8[r];   // idx
            ob[131072 + (size_t)tg * TOPK + r] = ev[r] * inv;     // weight
        }
    }
#undef BADDR
#undef LOADB
#undef CMP
#undef VMW
}

extern "C" void kernel_launch(void* const* d_in, const int* in_sizes, int n_in,
                              void* d_out, int out_size, void* d_ws, size_t ws_size,
                              hipStream_t stream) {
    const float* hs = (const float*)d_in[0];   // [16384, 7168] f32
    const float* wt = (const float*)d_in[1];   // [256, 7168] f32
    float* ob = (float*)d_out;                 // f32[393216]: idx | weight | row

    wconv_frag<<<dim3(NEXP * HID / 8 / 256), dim3(256), 0, stream>>>(wt);
    moe_gate_v17<<<dim3(NTOK / 32), dim3(512), 0, stream>>>(hs, ob);
    moe_rows<<<dim3(512), dim3(256), 0, stream>>>(ob);
}